// Round 2
// baseline (600.586 us; speedup 1.0000x reference)
//
#include <hip/hip_runtime.h>
#include <hip/hip_bf16.h>
#include <math.h>

#define B_ 4
#define S_ 2048
#define D_ 1024
#define H_ 16
#define HD_ 64
#define M_TOT (B_*S_)   // 8192

typedef __attribute__((ext_vector_type(4))) float f32x4;
typedef __attribute__((ext_vector_type(8))) short s16x8;

__device__ inline short f2bf(float f) {
  __hip_bfloat16 h = __float2bfloat16(f);
  return *reinterpret_cast<short*>(&h);
}

__device__ inline f32x4 mfma16(s16x8 a, s16x8 b, f32x4 c) {
  return __builtin_amdgcn_mfma_f32_16x16x32_bf16(a, b, c, 0, 0, 0);
}

// ---------------- cast x: fp32 -> bf16 ----------------
__global__ __launch_bounds__(256) void cast_x_kernel(const float* __restrict__ in,
                                                     short* __restrict__ out) {
  int i = (blockIdx.x * 256 + threadIdx.x) * 8;
  float4 v0 = *(const float4*)(in + i);
  float4 v1 = *(const float4*)(in + i + 4);
  s16x8 o;
  o[0]=f2bf(v0.x); o[1]=f2bf(v0.y); o[2]=f2bf(v0.z); o[3]=f2bf(v0.w);
  o[4]=f2bf(v1.x); o[5]=f2bf(v1.y); o[6]=f2bf(v1.z); o[7]=f2bf(v1.w);
  *(s16x8*)(out + i) = o;
}

// ---------------- transpose + cast weights: W[k][n] fp32 -> WT[n][k] bf16 ----------------
__global__ __launch_bounds__(256) void transpose_cast_kernel(
    const float* __restrict__ W0, const float* __restrict__ W1,
    const float* __restrict__ W2, const float* __restrict__ W3,
    short* __restrict__ T0, short* __restrict__ T1,
    short* __restrict__ T2, short* __restrict__ T3) {
  const float* W; short* T;
  switch (blockIdx.z) {
    case 0: W = W0; T = T0; break;
    case 1: W = W1; T = T1; break;
    case 2: W = W2; T = T2; break;
    default: W = W3; T = T3; break;
  }
  __shared__ float tile[32][33];
  int x = blockIdx.x * 32 + threadIdx.x;           // n
  int y0 = blockIdx.y * 32;                        // k base
  for (int j = threadIdx.y; j < 32; j += 8)
    tile[j][threadIdx.x] = W[(y0 + j) * D_ + x];
  __syncthreads();
  int x2 = blockIdx.y * 32 + threadIdx.x;          // k
  int y2 = blockIdx.x * 32;                        // n base
  for (int j = threadIdx.y; j < 32; j += 8)
    T[(y2 + j) * D_ + x2] = f2bf(tile[threadIdx.x][j]);
}

// ---------------- GEMM: C = A[M,K] @ Bt[N,K]^T, 128x128 tile, 4 waves ----------------
// epilogue z=0 -> Qb[b,h,s,d] bf16 ; z=1 -> Kb same ; z=2 -> Vt[b,h,d,s] bf16
__global__ __launch_bounds__(256) void gemm_qkv_kernel(
    const short* __restrict__ A,
    const short* __restrict__ WqT, const short* __restrict__ WkT, const short* __restrict__ WvT,
    short* __restrict__ Qb, short* __restrict__ Kb, short* __restrict__ Vt) {
  const int z = blockIdx.z;
  const short* Bt = (z == 0) ? WqT : (z == 1) ? WkT : WvT;
  __shared__ short sA[128 * 32];
  __shared__ short sB[128 * 32];
  const int tid = threadIdx.x;
  const int w = tid >> 6, l = tid & 63;
  const int wr = w >> 1, wc = w & 1;
  const int tm = blockIdx.x * 128, tn = blockIdx.y * 128;
  const int trow = tid >> 2, tcol = (tid & 3) * 8;
  const int lr = l & 15, lk = (l >> 4) * 8;
  f32x4 acc[4][4];
#pragma unroll
  for (int i = 0; i < 4; ++i)
#pragma unroll
    for (int j = 0; j < 4; ++j) acc[i][j] = (f32x4){0.f, 0.f, 0.f, 0.f};

  const short* Arow0 = A + (size_t)(tm + trow) * D_ + tcol;
  const short* Arow1 = A + (size_t)(tm + 64 + trow) * D_ + tcol;
  const short* Brow0 = Bt + (size_t)(tn + trow) * D_ + tcol;
  const short* Brow1 = Bt + (size_t)(tn + 64 + trow) * D_ + tcol;

  for (int k0 = 0; k0 < D_; k0 += 32) {
    s16x8 a0 = *(const s16x8*)(Arow0 + k0);
    s16x8 a1 = *(const s16x8*)(Arow1 + k0);
    s16x8 b0 = *(const s16x8*)(Brow0 + k0);
    s16x8 b1 = *(const s16x8*)(Brow1 + k0);
    __syncthreads();
    *(s16x8*)(sA + trow * 32 + tcol) = a0;
    *(s16x8*)(sA + (64 + trow) * 32 + tcol) = a1;
    *(s16x8*)(sB + trow * 32 + tcol) = b0;
    *(s16x8*)(sB + (64 + trow) * 32 + tcol) = b1;
    __syncthreads();
    s16x8 af[4], bfr[4];
#pragma unroll
    for (int mi = 0; mi < 4; ++mi)
      af[mi] = *(const s16x8*)(sA + (wr * 64 + mi * 16 + lr) * 32 + lk);
#pragma unroll
    for (int ni = 0; ni < 4; ++ni)
      bfr[ni] = *(const s16x8*)(sB + (wc * 64 + ni * 16 + lr) * 32 + lk);
#pragma unroll
    for (int mi = 0; mi < 4; ++mi)
#pragma unroll
      for (int ni = 0; ni < 4; ++ni)
        acc[mi][ni] = mfma16(af[mi], bfr[ni], acc[mi][ni]);
  }
#pragma unroll
  for (int mi = 0; mi < 4; ++mi)
#pragma unroll
    for (int ni = 0; ni < 4; ++ni)
#pragma unroll
      for (int r = 0; r < 4; ++r) {
        int row = tm + wr * 64 + mi * 16 + (l >> 4) * 4 + r;
        int col = tn + wc * 64 + ni * 16 + lr;
        int b = row >> 11, s = row & 2047;
        int h = col >> 6, d = col & 63;
        short v = f2bf(acc[mi][ni][r]);
        if (z == 0)
          Qb[((size_t)(b * H_ + h) * S_ + s) * HD_ + d] = v;
        else if (z == 1)
          Kb[((size_t)(b * H_ + h) * S_ + s) * HD_ + d] = v;
        else
          Vt[((size_t)(b * H_ + h) * HD_ + d) * S_ + s] = v;
      }
}

// ---------------- GEMM: out = ctxb @ WoT^T, fp32 epilogue ----------------
__global__ __launch_bounds__(256) void gemm_out_kernel(
    const short* __restrict__ A, const short* __restrict__ Bt, float* __restrict__ out) {
  __shared__ short sA[128 * 32];
  __shared__ short sB[128 * 32];
  const int tid = threadIdx.x;
  const int w = tid >> 6, l = tid & 63;
  const int wr = w >> 1, wc = w & 1;
  const int tm = blockIdx.x * 128, tn = blockIdx.y * 128;
  const int trow = tid >> 2, tcol = (tid & 3) * 8;
  const int lr = l & 15, lk = (l >> 4) * 8;
  f32x4 acc[4][4];
#pragma unroll
  for (int i = 0; i < 4; ++i)
#pragma unroll
    for (int j = 0; j < 4; ++j) acc[i][j] = (f32x4){0.f, 0.f, 0.f, 0.f};

  const short* Arow0 = A + (size_t)(tm + trow) * D_ + tcol;
  const short* Arow1 = A + (size_t)(tm + 64 + trow) * D_ + tcol;
  const short* Brow0 = Bt + (size_t)(tn + trow) * D_ + tcol;
  const short* Brow1 = Bt + (size_t)(tn + 64 + trow) * D_ + tcol;

  for (int k0 = 0; k0 < D_; k0 += 32) {
    s16x8 a0 = *(const s16x8*)(Arow0 + k0);
    s16x8 a1 = *(const s16x8*)(Arow1 + k0);
    s16x8 b0 = *(const s16x8*)(Brow0 + k0);
    s16x8 b1 = *(const s16x8*)(Brow1 + k0);
    __syncthreads();
    *(s16x8*)(sA + trow * 32 + tcol) = a0;
    *(s16x8*)(sA + (64 + trow) * 32 + tcol) = a1;
    *(s16x8*)(sB + trow * 32 + tcol) = b0;
    *(s16x8*)(sB + (64 + trow) * 32 + tcol) = b1;
    __syncthreads();
    s16x8 af[4], bfr[4];
#pragma unroll
    for (int mi = 0; mi < 4; ++mi)
      af[mi] = *(const s16x8*)(sA + (wr * 64 + mi * 16 + lr) * 32 + lk);
#pragma unroll
    for (int ni = 0; ni < 4; ++ni)
      bfr[ni] = *(const s16x8*)(sB + (wc * 64 + ni * 16 + lr) * 32 + lk);
#pragma unroll
    for (int mi = 0; mi < 4; ++mi)
#pragma unroll
      for (int ni = 0; ni < 4; ++ni)
        acc[mi][ni] = mfma16(af[mi], bfr[ni], acc[mi][ni]);
  }
#pragma unroll
  for (int mi = 0; mi < 4; ++mi)
#pragma unroll
    for (int ni = 0; ni < 4; ++ni)
#pragma unroll
      for (int r = 0; r < 4; ++r) {
        int row = tm + wr * 64 + mi * 16 + (l >> 4) * 4 + r;
        int col = tn + wc * 64 + ni * 16 + lr;
        out[(size_t)row * D_ + col] = acc[mi][ni][r];
      }
}

// ---------------- flash attention, causal ----------------
// block: (qt, bh); 4 waves, each owns 16 q-rows. Q/K read direct (L2-fit), V via Vt.
__global__ __launch_bounds__(256) void attn_kernel(
    const short* __restrict__ Qb, const short* __restrict__ Kb,
    const short* __restrict__ Vt, short* __restrict__ ctx) {
  __shared__ short sP[4][16 * 32];
  const int qt = blockIdx.x;   // 0..31
  const int bh = blockIdx.y;   // 0..63
  const int b = bh >> 4, h = bh & 15;
  const int tid = threadIdx.x;
  const int w = tid >> 6, l = tid & 63;
  const int lr = l & 15, lk = (l >> 4) * 8;
  const int q0 = qt * 64 + w * 16;
  const short* Q  = Qb + (size_t)bh * S_ * HD_;
  const short* Kp = Kb + (size_t)bh * S_ * HD_;
  const short* Vp = Vt + (size_t)bh * HD_ * S_;

  s16x8 qf0 = *(const s16x8*)(Q + (q0 + lr) * HD_ + lk);
  s16x8 qf1 = *(const s16x8*)(Q + (q0 + lr) * HD_ + 32 + lk);

  f32x4 o[4];
#pragma unroll
  for (int i = 0; i < 4; ++i) o[i] = (f32x4){0.f, 0.f, 0.f, 0.f};
  float mrow[4] = {-INFINITY, -INFINITY, -INFINITY, -INFINITY};
  float lsum[4] = {0.f, 0.f, 0.f, 0.f};

  const int ktend = 2 * qt + 2;  // uniform across waves (waves 0-1 get one fully-masked tile)
  for (int kt = 0; kt < ktend; ++kt) {
    const int kb = kt * 32;
    f32x4 sc[2];
#pragma unroll
    for (int nt = 0; nt < 2; ++nt) {
      s16x8 kf0 = *(const s16x8*)(Kp + (kb + nt * 16 + lr) * HD_ + lk);
      s16x8 kf1 = *(const s16x8*)(Kp + (kb + nt * 16 + lr) * HD_ + 32 + lk);
      f32x4 c = (f32x4){0.f, 0.f, 0.f, 0.f};
      c = mfma16(qf0, kf0, c);
      c = mfma16(qf1, kf1, c);
      sc[nt] = c;
    }
    float p0v[4], p1v[4], alpha[4];
#pragma unroll
    for (int r = 0; r < 4; ++r) {
      int qrow = q0 + (l >> 4) * 4 + r;
      float s0 = (kb + lr)      <= qrow ? sc[0][r] * 0.125f : -INFINITY;
      float s1 = (kb + 16 + lr) <= qrow ? sc[1][r] * 0.125f : -INFINITY;
      float mt = fmaxf(s0, s1);
      mt = fmaxf(mt, __shfl_xor(mt, 8));
      mt = fmaxf(mt, __shfl_xor(mt, 4));
      mt = fmaxf(mt, __shfl_xor(mt, 2));
      mt = fmaxf(mt, __shfl_xor(mt, 1));
      float mn = fmaxf(mrow[r], mt);   // finite after kt=0 (k=0 always valid)
      float a = expf(mrow[r] - mn);    // mrow=-inf,mn finite -> 0 ; masked tile: mn=mrow -> 1
      float p0 = expf(s0 - mn);
      float p1 = expf(s1 - mn);
      float rs = p0 + p1;
      rs += __shfl_xor(rs, 8); rs += __shfl_xor(rs, 4);
      rs += __shfl_xor(rs, 2); rs += __shfl_xor(rs, 1);
      lsum[r] = lsum[r] * a + rs;
      mrow[r] = mn;
      alpha[r] = a;
      p0v[r] = p0; p1v[r] = p1;
    }
#pragma unroll
    for (int ni = 0; ni < 4; ++ni)
#pragma unroll
      for (int r = 0; r < 4; ++r) o[ni][r] *= alpha[r];
    __syncthreads();
#pragma unroll
    for (int r = 0; r < 4; ++r) {
      sP[w][((l >> 4) * 4 + r) * 32 + lr] = f2bf(p0v[r]);
      sP[w][((l >> 4) * 4 + r) * 32 + 16 + lr] = f2bf(p1v[r]);
    }
    __syncthreads();
    s16x8 pf = *(const s16x8*)(&sP[w][lr * 32 + lk]);
#pragma unroll
    for (int ni = 0; ni < 4; ++ni) {
      s16x8 vf = *(const s16x8*)(Vp + (ni * 16 + lr) * S_ + kb + lk);
      o[ni] = mfma16(pf, vf, o[ni]);
    }
  }
#pragma unroll
  for (int ni = 0; ni < 4; ++ni)
#pragma unroll
    for (int r = 0; r < 4; ++r) {
      int qrow = q0 + (l >> 4) * 4 + r;
      float val = o[ni][r] / lsum[r];
      ctx[((size_t)(b * S_ + qrow)) * D_ + h * HD_ + ni * 16 + lr] = f2bf(val);
    }
}

extern "C" void kernel_launch(void* const* d_in, const int* in_sizes, int n_in,
                              void* d_out, int out_size, void* d_ws, size_t ws_size,
                              hipStream_t stream) {
  const float* x  = (const float*)d_in[0];
  const float* Wq = (const float*)d_in[1];
  const float* Wk = (const float*)d_in[2];
  const float* Wv = (const float*)d_in[3];
  const float* Wo = (const float*)d_in[4];
  float* out = (float*)d_out;

  char* ws = (char*)d_ws;
  size_t off = 0;
  auto alloc = [&](size_t bytes) {
    void* p = ws + off;
    off += (bytes + 255) & ~(size_t)255;
    return p;
  };
  short* xb   = (short*)alloc((size_t)M_TOT * D_ * 2);
  short* WqT  = (short*)alloc((size_t)D_ * D_ * 2);
  short* WkT  = (short*)alloc((size_t)D_ * D_ * 2);
  short* WvT  = (short*)alloc((size_t)D_ * D_ * 2);
  short* WoT  = (short*)alloc((size_t)D_ * D_ * 2);
  short* Qb   = (short*)alloc((size_t)B_ * H_ * S_ * HD_ * 2);
  short* Kb   = (short*)alloc((size_t)B_ * H_ * S_ * HD_ * 2);
  short* Vt   = (short*)alloc((size_t)B_ * H_ * S_ * HD_ * 2);
  short* ctxb = (short*)alloc((size_t)M_TOT * D_ * 2);

  cast_x_kernel<<<(M_TOT * D_) / (256 * 8), 256, 0, stream>>>(x, xb);
  transpose_cast_kernel<<<dim3(D_ / 32, D_ / 32, 4), dim3(32, 8, 1), 0, stream>>>(
      Wq, Wk, Wv, Wo, WqT, WkT, WvT, WoT);
  gemm_qkv_kernel<<<dim3(M_TOT / 128, D_ / 128, 3), 256, 0, stream>>>(
      xb, WqT, WkT, WvT, Qb, Kb, Vt);
  attn_kernel<<<dim3(S_ / 64, B_ * H_), 256, 0, stream>>>(Qb, Kb, Vt, ctxb);
  gemm_out_kernel<<<dim3(M_TOT / 128, D_ / 128), 256, 0, stream>>>(ctxb, WoT, out);
}

// Round 3
// 300.385 us; speedup vs baseline: 1.9994x; 1.9994x over previous
//
#include <hip/hip_runtime.h>
#include <hip/hip_bf16.h>
#include <math.h>

#define B_ 4
#define S_ 2048
#define D_ 1024
#define H_ 16
#define HD_ 64
#define M_TOT (B_*S_)   // 8192

typedef __attribute__((ext_vector_type(4))) float f32x4;
typedef __attribute__((ext_vector_type(16))) float f32x16;
typedef __attribute__((ext_vector_type(8))) short s16x8;
typedef __attribute__((ext_vector_type(4))) unsigned u32x4;

__device__ inline short f2bf(float f) {
  __hip_bfloat16 h = __float2bfloat16(f);
  return *reinterpret_cast<short*>(&h);
}

__device__ inline unsigned pkbf(float lo, float hi) {
  return (unsigned)(unsigned short)f2bf(lo) | ((unsigned)(unsigned short)f2bf(hi) << 16);
}

__device__ inline f32x4 mfma16(s16x8 a, s16x8 b, f32x4 c) {
  return __builtin_amdgcn_mfma_f32_16x16x32_bf16(a, b, c, 0, 0, 0);
}
__device__ inline f32x16 mfma32(s16x8 a, s16x8 b, f32x16 c) {
  return __builtin_amdgcn_mfma_f32_32x32x16_bf16(a, b, c, 0, 0, 0);
}

// ---------------- cast x: fp32 -> bf16 ----------------
__global__ __launch_bounds__(256) void cast_x_kernel(const float* __restrict__ in,
                                                     short* __restrict__ out) {
  int i = (blockIdx.x * 256 + threadIdx.x) * 8;
  float4 v0 = *(const float4*)(in + i);
  float4 v1 = *(const float4*)(in + i + 4);
  s16x8 o;
  o[0]=f2bf(v0.x); o[1]=f2bf(v0.y); o[2]=f2bf(v0.z); o[3]=f2bf(v0.w);
  o[4]=f2bf(v1.x); o[5]=f2bf(v1.y); o[6]=f2bf(v1.z); o[7]=f2bf(v1.w);
  *(s16x8*)(out + i) = o;
}

// ---------------- transpose + cast weights: W[k][n] fp32 -> WT[n][k] bf16 ----------------
__global__ __launch_bounds__(256) void transpose_cast_kernel(
    const float* __restrict__ W0, const float* __restrict__ W1,
    const float* __restrict__ W2, const float* __restrict__ W3,
    short* __restrict__ T0, short* __restrict__ T1,
    short* __restrict__ T2, short* __restrict__ T3) {
  const float* W; short* T;
  switch (blockIdx.z) {
    case 0: W = W0; T = T0; break;
    case 1: W = W1; T = T1; break;
    case 2: W = W2; T = T2; break;
    default: W = W3; T = T3; break;
  }
  __shared__ float tile[32][33];
  int x = blockIdx.x * 32 + threadIdx.x;
  int y0 = blockIdx.y * 32;
  for (int j = threadIdx.y; j < 32; j += 8)
    tile[j][threadIdx.x] = W[(y0 + j) * D_ + x];
  __syncthreads();
  int x2 = blockIdx.y * 32 + threadIdx.x;
  int y2 = blockIdx.x * 32;
  for (int j = threadIdx.y; j < 32; j += 8)
    T[(y2 + j) * D_ + x2] = f2bf(tile[threadIdx.x][j]);
}

// ---------------- GEMM: C = A[M,K] @ Bt[N,K]^T, 128x128 tile, 4 waves ----------------
// z=0 -> Qb (pre-scaled by 0.125*log2e) ; z=1 -> Kb ; z=2 -> Vt[b,h,d,s]
__global__ __launch_bounds__(256) void gemm_qkv_kernel(
    const short* __restrict__ A,
    const short* __restrict__ WqT, const short* __restrict__ WkT, const short* __restrict__ WvT,
    short* __restrict__ Qb, short* __restrict__ Kb, short* __restrict__ Vt) {
  const int z = blockIdx.z;
  const short* Bt = (z == 0) ? WqT : (z == 1) ? WkT : WvT;
  __shared__ short sA[128 * 32];
  __shared__ short sB[128 * 32];
  const int tid = threadIdx.x;
  const int w = tid >> 6, l = tid & 63;
  const int wr = w >> 1, wc = w & 1;
  const int tm = blockIdx.x * 128, tn = blockIdx.y * 128;
  const int trow = tid >> 2, tcol = (tid & 3) * 8;
  const int lr = l & 15, lk = (l >> 4) * 8;
  f32x4 acc[4][4];
#pragma unroll
  for (int i = 0; i < 4; ++i)
#pragma unroll
    for (int j = 0; j < 4; ++j) acc[i][j] = (f32x4){0.f, 0.f, 0.f, 0.f};

  const short* Arow0 = A + (size_t)(tm + trow) * D_ + tcol;
  const short* Arow1 = A + (size_t)(tm + 64 + trow) * D_ + tcol;
  const short* Brow0 = Bt + (size_t)(tn + trow) * D_ + tcol;
  const short* Brow1 = Bt + (size_t)(tn + 64 + trow) * D_ + tcol;

  for (int k0 = 0; k0 < D_; k0 += 32) {
    s16x8 a0 = *(const s16x8*)(Arow0 + k0);
    s16x8 a1 = *(const s16x8*)(Arow1 + k0);
    s16x8 b0 = *(const s16x8*)(Brow0 + k0);
    s16x8 b1 = *(const s16x8*)(Brow1 + k0);
    __syncthreads();
    *(s16x8*)(sA + trow * 32 + tcol) = a0;
    *(s16x8*)(sA + (64 + trow) * 32 + tcol) = a1;
    *(s16x8*)(sB + trow * 32 + tcol) = b0;
    *(s16x8*)(sB + (64 + trow) * 32 + tcol) = b1;
    __syncthreads();
    s16x8 af[4], bfr[4];
#pragma unroll
    for (int mi = 0; mi < 4; ++mi)
      af[mi] = *(const s16x8*)(sA + (wr * 64 + mi * 16 + lr) * 32 + lk);
#pragma unroll
    for (int ni = 0; ni < 4; ++ni)
      bfr[ni] = *(const s16x8*)(sB + (wc * 64 + ni * 16 + lr) * 32 + lk);
#pragma unroll
    for (int mi = 0; mi < 4; ++mi)
#pragma unroll
      for (int ni = 0; ni < 4; ++ni)
        acc[mi][ni] = mfma16(af[mi], bfr[ni], acc[mi][ni]);
  }
  const float qscale = 0.18033688011112042f;  // 0.125 * log2(e)
#pragma unroll
  for (int mi = 0; mi < 4; ++mi)
#pragma unroll
    for (int ni = 0; ni < 4; ++ni)
#pragma unroll
      for (int r = 0; r < 4; ++r) {
        int row = tm + wr * 64 + mi * 16 + (l >> 4) * 4 + r;
        int col = tn + wc * 64 + ni * 16 + lr;
        int b = row >> 11, s = row & 2047;
        int h = col >> 6, d = col & 63;
        float av = acc[mi][ni][r];
        if (z == 0)
          Qb[((size_t)(b * H_ + h) * S_ + s) * HD_ + d] = f2bf(av * qscale);
        else if (z == 1)
          Kb[((size_t)(b * H_ + h) * S_ + s) * HD_ + d] = f2bf(av);
        else
          Vt[((size_t)(b * H_ + h) * HD_ + d) * S_ + s] = f2bf(av);
      }
}

// ---------------- GEMM: out = ctxb @ WoT^T, fp32 epilogue ----------------
__global__ __launch_bounds__(256) void gemm_out_kernel(
    const short* __restrict__ A, const short* __restrict__ Bt, float* __restrict__ out) {
  __shared__ short sA[128 * 32];
  __shared__ short sB[128 * 32];
  const int tid = threadIdx.x;
  const int w = tid >> 6, l = tid & 63;
  const int wr = w >> 1, wc = w & 1;
  const int tm = blockIdx.x * 128, tn = blockIdx.y * 128;
  const int trow = tid >> 2, tcol = (tid & 3) * 8;
  const int lr = l & 15, lk = (l >> 4) * 8;
  f32x4 acc[4][4];
#pragma unroll
  for (int i = 0; i < 4; ++i)
#pragma unroll
    for (int j = 0; j < 4; ++j) acc[i][j] = (f32x4){0.f, 0.f, 0.f, 0.f};

  const short* Arow0 = A + (size_t)(tm + trow) * D_ + tcol;
  const short* Arow1 = A + (size_t)(tm + 64 + trow) * D_ + tcol;
  const short* Brow0 = Bt + (size_t)(tn + trow) * D_ + tcol;
  const short* Brow1 = Bt + (size_t)(tn + 64 + trow) * D_ + tcol;

  for (int k0 = 0; k0 < D_; k0 += 32) {
    s16x8 a0 = *(const s16x8*)(Arow0 + k0);
    s16x8 a1 = *(const s16x8*)(Arow1 + k0);
    s16x8 b0 = *(const s16x8*)(Brow0 + k0);
    s16x8 b1 = *(const s16x8*)(Brow1 + k0);
    __syncthreads();
    *(s16x8*)(sA + trow * 32 + tcol) = a0;
    *(s16x8*)(sA + (64 + trow) * 32 + tcol) = a1;
    *(s16x8*)(sB + trow * 32 + tcol) = b0;
    *(s16x8*)(sB + (64 + trow) * 32 + tcol) = b1;
    __syncthreads();
    s16x8 af[4], bfr[4];
#pragma unroll
    for (int mi = 0; mi < 4; ++mi)
      af[mi] = *(const s16x8*)(sA + (wr * 64 + mi * 16 + lr) * 32 + lk);
#pragma unroll
    for (int ni = 0; ni < 4; ++ni)
      bfr[ni] = *(const s16x8*)(sB + (wc * 64 + ni * 16 + lr) * 32 + lk);
#pragma unroll
    for (int mi = 0; mi < 4; ++mi)
#pragma unroll
      for (int ni = 0; ni < 4; ++ni)
        acc[mi][ni] = mfma16(af[mi], bfr[ni], acc[mi][ni]);
  }
#pragma unroll
  for (int mi = 0; mi < 4; ++mi)
#pragma unroll
    for (int ni = 0; ni < 4; ++ni)
#pragma unroll
      for (int r = 0; r < 4; ++r) {
        int row = tm + wr * 64 + mi * 16 + (l >> 4) * 4 + r;
        int col = tn + wc * 64 + ni * 16 + lr;
        out[(size_t)row * D_ + col] = acc[mi][ni][r];
      }
}

// ---------------- flash attention, causal, 32x32 swapped-operand, all-register ----------------
// 1024 blocks x 256 thr; 4 waves/block, each wave owns 32 q rows. No barriers in main loop.
// scores^T = mfma32(Kfrag, Qfrag): lane holds S^T[kv=(r&3)+8*(r>>2)+4*hi5][q=l&31]
// O^T     = mfma32(Vtfrag, Pfrag): lane holds O^T[hd=32t+(r&3)+8*(r>>2)+4*hi5][q=l&31]
__global__ __launch_bounds__(256) void attn_kernel(
    const short* __restrict__ Qb, const short* __restrict__ Kb,
    const short* __restrict__ Vt, short* __restrict__ ctx) {
  __shared__ short sO[4][32 * 72];
  const int bid = blockIdx.x;                    // 0..1023
  const int swz = (bid & 7) * 128 + (bid >> 3);  // XCD-chunked: 8 bh per XCD
  const int bh = swz >> 4;
  const int qt = 15 - (swz & 15);                // heavy q-tiles first
  const int b = bh >> 4, h = bh & 15;
  const int tid = threadIdx.x;
  const int w = tid >> 6, l = tid & 63;
  const int q31 = l & 31, hi5 = l >> 5;
  const int qw = qt * 128 + w * 32;              // wave's q base (32-aligned)
  const short* Qp = Qb + (size_t)bh * S_ * HD_;
  const short* Kp = Kb + (size_t)bh * S_ * HD_;
  const short* Vp = Vt + (size_t)bh * HD_ * S_;

  s16x8 qf[4];
#pragma unroll
  for (int c = 0; c < 4; ++c)
    qf[c] = *(const s16x8*)(Qp + (qw + q31) * HD_ + c * 16 + hi5 * 8);

  f32x16 ot0, ot1;
#pragma unroll
  for (int r = 0; r < 16; ++r) { ot0[r] = 0.f; ot1[r] = 0.f; }
  float mrow = -1e30f, lsum = 0.f;

  const int ntile = qw / 32 + 1;
  for (int t = 0; t < ntile; ++t) {
    const int kv0 = t * 32;
    s16x8 kf[4], vf0[2], vf1[2];
#pragma unroll
    for (int c = 0; c < 4; ++c)
      kf[c] = *(const s16x8*)(Kp + (kv0 + q31) * HD_ + c * 16 + hi5 * 8);
#pragma unroll
    for (int kc = 0; kc < 2; ++kc) {
      vf0[kc] = *(const s16x8*)(Vp + q31 * S_ + kv0 + kc * 16 + hi5 * 8);
      vf1[kc] = *(const s16x8*)(Vp + (32 + q31) * S_ + kv0 + kc * 16 + hi5 * 8);
    }
    f32x16 s;
#pragma unroll
    for (int r = 0; r < 16; ++r) s[r] = 0.f;
    s = mfma32(kf[0], qf[0], s);
    s = mfma32(kf[1], qf[1], s);
    s = mfma32(kf[2], qf[2], s);
    s = mfma32(kf[3], qf[3], s);

    if (t == ntile - 1) {  // diagonal tile: mask kv > q
#pragma unroll
      for (int r = 0; r < 16; ++r) {
        int kvpat = (r & 3) + 8 * (r >> 2) + 4 * hi5;
        if (kvpat > q31) s[r] = -1e30f;
      }
    }
    // row max (q is lane-local; kv split over regs + partner lane)
    float m = s[0];
#pragma unroll
    for (int r = 1; r < 16; ++r) m = fmaxf(m, s[r]);
    m = fmaxf(m, __shfl_xor(m, 32));
    float mn = fmaxf(mrow, m);
    float alpha = exp2f(mrow - mn);
    float p[16];
    float rs = 0.f;
#pragma unroll
    for (int r = 0; r < 16; ++r) { p[r] = exp2f(s[r] - mn); rs += p[r]; }
    rs += __shfl_xor(rs, 32);
    lsum = lsum * alpha + rs;
    mrow = mn;
#pragma unroll
    for (int r = 0; r < 16; ++r) { ot0[r] *= alpha; ot1[r] *= alpha; }

    // P -> B-fragment (rows q=l&31, k=kv): pack + cross-half shuffle + select
    unsigned pk01 = pkbf(p[0], p[1]),  pk23 = pkbf(p[2], p[3]);
    unsigned pk45 = pkbf(p[4], p[5]),  pk67 = pkbf(p[6], p[7]);
    unsigned pk89 = pkbf(p[8], p[9]),  pkAB = pkbf(p[10], p[11]);
    unsigned pkCD = pkbf(p[12], p[13]), pkEF = pkbf(p[14], p[15]);
    unsigned sx01 = (unsigned)__shfl_xor((int)pk01, 32);
    unsigned sx23 = (unsigned)__shfl_xor((int)pk23, 32);
    unsigned sx45 = (unsigned)__shfl_xor((int)pk45, 32);
    unsigned sx67 = (unsigned)__shfl_xor((int)pk67, 32);
    unsigned sx89 = (unsigned)__shfl_xor((int)pk89, 32);
    unsigned sxAB = (unsigned)__shfl_xor((int)pkAB, 32);
    unsigned sxCD = (unsigned)__shfl_xor((int)pkCD, 32);
    unsigned sxEF = (unsigned)__shfl_xor((int)pkEF, 32);
    union { u32x4 u; s16x8 v; } c0, c1;
    c0.u = hi5 ? (u32x4){sx45, sx67, pk45, pk67} : (u32x4){pk01, pk23, sx01, sx23};
    c1.u = hi5 ? (u32x4){sxCD, sxEF, pkCD, pkEF} : (u32x4){pk89, pkAB, sx89, sxAB};
    s16x8 pf0 = c0.v, pf1 = c1.v;

    ot0 = mfma32(vf0[0], pf0, ot0);
    ot0 = mfma32(vf0[1], pf1, ot0);
    ot1 = mfma32(vf1[0], pf0, ot1);
    ot1 = mfma32(vf1[1], pf1, ot1);
  }

  // epilogue: O^T regs -> per-wave LDS -> coalesced ctx rows
  float rl = 1.0f / lsum;
  short* so = &sO[w][0];
#pragma unroll
  for (int t = 0; t < 2; ++t)
#pragma unroll
    for (int g = 0; g < 4; ++g) {
      float v0 = (t ? ot1[4 * g + 0] : ot0[4 * g + 0]) * rl;
      float v1 = (t ? ot1[4 * g + 1] : ot0[4 * g + 1]) * rl;
      float v2 = (t ? ot1[4 * g + 2] : ot0[4 * g + 2]) * rl;
      float v3 = (t ? ot1[4 * g + 3] : ot0[4 * g + 3]) * rl;
      int hdb = 32 * t + 8 * g + 4 * hi5;
      *(uint2*)(so + q31 * 72 + hdb) = make_uint2(pkbf(v0, v1), pkbf(v2, v3));
    }
  __syncthreads();  // intra-wave LDS visibility (cheap: once per kernel)
#pragma unroll
  for (int i = 0; i < 4; ++i) {
    int rr = l >> 1;
    int cb = (l & 1) * 8 + i * 16;
    s16x8 ov = *(const s16x8*)(so + rr * 72 + cb);
    *(s16x8*)(ctx + ((size_t)(b * S_ + qt * 128 + w * 32 + rr)) * D_ + h * 64 + cb) = ov;
  }
}

extern "C" void kernel_launch(void* const* d_in, const int* in_sizes, int n_in,
                              void* d_out, int out_size, void* d_ws, size_t ws_size,
                              hipStream_t stream) {
  const float* x  = (const float*)d_in[0];
  const float* Wq = (const float*)d_in[1];
  const float* Wk = (const float*)d_in[2];
  const float* Wv = (const float*)d_in[3];
  const float* Wo = (const float*)d_in[4];
  float* out = (float*)d_out;

  char* ws = (char*)d_ws;
  size_t off = 0;
  auto alloc = [&](size_t bytes) {
    void* p = ws + off;
    off += (bytes + 255) & ~(size_t)255;
    return p;
  };
  short* xb   = (short*)alloc((size_t)M_TOT * D_ * 2);
  short* WqT  = (short*)alloc((size_t)D_ * D_ * 2);
  short* WkT  = (short*)alloc((size_t)D_ * D_ * 2);
  short* WvT  = (short*)alloc((size_t)D_ * D_ * 2);
  short* WoT  = (short*)alloc((size_t)D_ * D_ * 2);
  short* Qb   = (short*)alloc((size_t)B_ * H_ * S_ * HD_ * 2);
  short* Kb   = (short*)alloc((size_t)B_ * H_ * S_ * HD_ * 2);
  short* Vt   = (short*)alloc((size_t)B_ * H_ * S_ * HD_ * 2);
  short* ctxb = (short*)alloc((size_t)M_TOT * D_ * 2);

  cast_x_kernel<<<(M_TOT * D_) / (256 * 8), 256, 0, stream>>>(x, xb);
  transpose_cast_kernel<<<dim3(D_ / 32, D_ / 32, 4), dim3(32, 8, 1), 0, stream>>>(
      Wq, Wk, Wv, Wo, WqT, WkT, WvT, WoT);
  gemm_qkv_kernel<<<dim3(M_TOT / 128, D_ / 128, 3), 256, 0, stream>>>(
      xb, WqT, WkT, WvT, Qb, Kb, Vt);
  attn_kernel<<<dim3(1024), 256, 0, stream>>>(Qb, Kb, Vt, ctxb);
  gemm_out_kernel<<<dim3(M_TOT / 128, D_ / 128), 256, 0, stream>>>(ctxb, WoT, out);
}

// Round 4
// 244.020 us; speedup vs baseline: 2.4612x; 1.2310x over previous
//
#include <hip/hip_runtime.h>
#include <hip/hip_bf16.h>
#include <math.h>

#define B_ 4
#define S_ 2048
#define D_ 1024
#define H_ 16
#define HD_ 64
#define M_TOT (B_*S_)   // 8192

typedef __attribute__((ext_vector_type(4))) float f32x4;
typedef __attribute__((ext_vector_type(16))) float f32x16;
typedef __attribute__((ext_vector_type(8))) short s16x8;
typedef __attribute__((ext_vector_type(4))) unsigned u32x4;

__device__ inline short f2bf(float f) {
  __hip_bfloat16 h = __float2bfloat16(f);
  return *reinterpret_cast<short*>(&h);
}

__device__ inline unsigned pkbf(float lo, float hi) {
  return (unsigned)(unsigned short)f2bf(lo) | ((unsigned)(unsigned short)f2bf(hi) << 16);
}

__device__ inline f32x4 mfma16(s16x8 a, s16x8 b, f32x4 c) {
  return __builtin_amdgcn_mfma_f32_16x16x32_bf16(a, b, c, 0, 0, 0);
}
__device__ inline f32x16 mfma32(s16x8 a, s16x8 b, f32x16 c) {
  return __builtin_amdgcn_mfma_f32_32x32x16_bf16(a, b, c, 0, 0, 0);
}

// ---------------- cast x: fp32 -> bf16 ----------------
__global__ __launch_bounds__(256) void cast_x_kernel(const float* __restrict__ in,
                                                     short* __restrict__ out) {
  int i = (blockIdx.x * 256 + threadIdx.x) * 8;
  float4 v0 = *(const float4*)(in + i);
  float4 v1 = *(const float4*)(in + i + 4);
  s16x8 o;
  o[0]=f2bf(v0.x); o[1]=f2bf(v0.y); o[2]=f2bf(v0.z); o[3]=f2bf(v0.w);
  o[4]=f2bf(v1.x); o[5]=f2bf(v1.y); o[6]=f2bf(v1.z); o[7]=f2bf(v1.w);
  *(s16x8*)(out + i) = o;
}

// ---------------- transpose + cast weights: W[k][n] fp32 -> WT[n][k] bf16 ----------------
__global__ __launch_bounds__(256) void transpose_cast_kernel(
    const float* __restrict__ W0, const float* __restrict__ W1,
    const float* __restrict__ W2, const float* __restrict__ W3,
    short* __restrict__ T0, short* __restrict__ T1,
    short* __restrict__ T2, short* __restrict__ T3) {
  const float* W; short* T;
  switch (blockIdx.z) {
    case 0: W = W0; T = T0; break;
    case 1: W = W1; T = T1; break;
    case 2: W = W2; T = T2; break;
    default: W = W3; T = T3; break;
  }
  __shared__ float tile[32][33];
  int x = blockIdx.x * 32 + threadIdx.x;
  int y0 = blockIdx.y * 32;
  for (int j = threadIdx.y; j < 32; j += 8)
    tile[j][threadIdx.x] = W[(y0 + j) * D_ + x];
  __syncthreads();
  int x2 = blockIdx.y * 32 + threadIdx.x;
  int y2 = blockIdx.x * 32;
  for (int j = threadIdx.y; j < 32; j += 8)
    T[(y2 + j) * D_ + x2] = f2bf(tile[threadIdx.x][j]);
}

// ---------------- GEMM: C = A[M,K] @ Bt[N,K]^T, 128x128 tile, 4 waves ----------------
// z=0 -> Qb (pre-scaled by 0.125*log2e) ; z=1 -> Kb ; z=2 -> Vt[b,h,d,s]
__global__ __launch_bounds__(256) void gemm_qkv_kernel(
    const short* __restrict__ A,
    const short* __restrict__ WqT, const short* __restrict__ WkT, const short* __restrict__ WvT,
    short* __restrict__ Qb, short* __restrict__ Kb, short* __restrict__ Vt) {
  const int z = blockIdx.z;
  const short* Bt = (z == 0) ? WqT : (z == 1) ? WkT : WvT;
  __shared__ short sA[128 * 32];
  __shared__ short sB[128 * 32];
  const int tid = threadIdx.x;
  const int w = tid >> 6, l = tid & 63;
  const int wr = w >> 1, wc = w & 1;
  const int tm = blockIdx.x * 128, tn = blockIdx.y * 128;
  const int trow = tid >> 2, tcol = (tid & 3) * 8;
  const int lr = l & 15, lk = (l >> 4) * 8;
  f32x4 acc[4][4];
#pragma unroll
  for (int i = 0; i < 4; ++i)
#pragma unroll
    for (int j = 0; j < 4; ++j) acc[i][j] = (f32x4){0.f, 0.f, 0.f, 0.f};

  const short* Arow0 = A + (size_t)(tm + trow) * D_ + tcol;
  const short* Arow1 = A + (size_t)(tm + 64 + trow) * D_ + tcol;
  const short* Brow0 = Bt + (size_t)(tn + trow) * D_ + tcol;
  const short* Brow1 = Bt + (size_t)(tn + 64 + trow) * D_ + tcol;

  for (int k0 = 0; k0 < D_; k0 += 32) {
    s16x8 a0 = *(const s16x8*)(Arow0 + k0);
    s16x8 a1 = *(const s16x8*)(Arow1 + k0);
    s16x8 b0 = *(const s16x8*)(Brow0 + k0);
    s16x8 b1 = *(const s16x8*)(Brow1 + k0);
    __syncthreads();
    *(s16x8*)(sA + trow * 32 + tcol) = a0;
    *(s16x8*)(sA + (64 + trow) * 32 + tcol) = a1;
    *(s16x8*)(sB + trow * 32 + tcol) = b0;
    *(s16x8*)(sB + (64 + trow) * 32 + tcol) = b1;
    __syncthreads();
    s16x8 af[4], bfr[4];
#pragma unroll
    for (int mi = 0; mi < 4; ++mi)
      af[mi] = *(const s16x8*)(sA + (wr * 64 + mi * 16 + lr) * 32 + lk);
#pragma unroll
    for (int ni = 0; ni < 4; ++ni)
      bfr[ni] = *(const s16x8*)(sB + (wc * 64 + ni * 16 + lr) * 32 + lk);
#pragma unroll
    for (int mi = 0; mi < 4; ++mi)
#pragma unroll
      for (int ni = 0; ni < 4; ++ni)
        acc[mi][ni] = mfma16(af[mi], bfr[ni], acc[mi][ni]);
  }
  const float qscale = 0.18033688011112042f;  // 0.125 * log2(e)
#pragma unroll
  for (int mi = 0; mi < 4; ++mi)
#pragma unroll
    for (int ni = 0; ni < 4; ++ni)
#pragma unroll
      for (int r = 0; r < 4; ++r) {
        int row = tm + wr * 64 + mi * 16 + (l >> 4) * 4 + r;
        int col = tn + wc * 64 + ni * 16 + lr;
        int b = row >> 11, s = row & 2047;
        int h = col >> 6, d = col & 63;
        float av = acc[mi][ni][r];
        if (z == 0)
          Qb[((size_t)(b * H_ + h) * S_ + s) * HD_ + d] = f2bf(av * qscale);
        else if (z == 1)
          Kb[((size_t)(b * H_ + h) * S_ + s) * HD_ + d] = f2bf(av);
        else
          Vt[((size_t)(b * H_ + h) * HD_ + d) * S_ + s] = f2bf(av);
      }
}

// ---------------- GEMM: out = ctxb @ WoT^T, fp32 epilogue ----------------
__global__ __launch_bounds__(256) void gemm_out_kernel(
    const short* __restrict__ A, const short* __restrict__ Bt, float* __restrict__ out) {
  __shared__ short sA[128 * 32];
  __shared__ short sB[128 * 32];
  const int tid = threadIdx.x;
  const int w = tid >> 6, l = tid & 63;
  const int wr = w >> 1, wc = w & 1;
  const int tm = blockIdx.x * 128, tn = blockIdx.y * 128;
  const int trow = tid >> 2, tcol = (tid & 3) * 8;
  const int lr = l & 15, lk = (l >> 4) * 8;
  f32x4 acc[4][4];
#pragma unroll
  for (int i = 0; i < 4; ++i)
#pragma unroll
    for (int j = 0; j < 4; ++j) acc[i][j] = (f32x4){0.f, 0.f, 0.f, 0.f};

  const short* Arow0 = A + (size_t)(tm + trow) * D_ + tcol;
  const short* Arow1 = A + (size_t)(tm + 64 + trow) * D_ + tcol;
  const short* Brow0 = Bt + (size_t)(tn + trow) * D_ + tcol;
  const short* Brow1 = Bt + (size_t)(tn + 64 + trow) * D_ + tcol;

  for (int k0 = 0; k0 < D_; k0 += 32) {
    s16x8 a0 = *(const s16x8*)(Arow0 + k0);
    s16x8 a1 = *(const s16x8*)(Arow1 + k0);
    s16x8 b0 = *(const s16x8*)(Brow0 + k0);
    s16x8 b1 = *(const s16x8*)(Brow1 + k0);
    __syncthreads();
    *(s16x8*)(sA + trow * 32 + tcol) = a0;
    *(s16x8*)(sA + (64 + trow) * 32 + tcol) = a1;
    *(s16x8*)(sB + trow * 32 + tcol) = b0;
    *(s16x8*)(sB + (64 + trow) * 32 + tcol) = b1;
    __syncthreads();
    s16x8 af[4], bfr[4];
#pragma unroll
    for (int mi = 0; mi < 4; ++mi)
      af[mi] = *(const s16x8*)(sA + (wr * 64 + mi * 16 + lr) * 32 + lk);
#pragma unroll
    for (int ni = 0; ni < 4; ++ni)
      bfr[ni] = *(const s16x8*)(sB + (wc * 64 + ni * 16 + lr) * 32 + lk);
#pragma unroll
    for (int mi = 0; mi < 4; ++mi)
#pragma unroll
      for (int ni = 0; ni < 4; ++ni)
        acc[mi][ni] = mfma16(af[mi], bfr[ni], acc[mi][ni]);
  }
#pragma unroll
  for (int mi = 0; mi < 4; ++mi)
#pragma unroll
    for (int ni = 0; ni < 4; ++ni)
#pragma unroll
      for (int r = 0; r < 4; ++r) {
        int row = tm + wr * 64 + mi * 16 + (l >> 4) * 4 + r;
        int col = tn + wc * 64 + ni * 16 + lr;
        out[(size_t)row * D_ + col] = acc[mi][ni][r];
      }
}

// ---------------- flash attention, causal, balanced strip-pairs ----------------
// 512 blocks x 256 thr. Block = (4 bh x 1 pair p); wave w -> bh = bhg*4+w.
// Each wave: strip p (nt=p+1 tiles) then strip 63-p (nt=64-p) => 65 tiles, uniform.
// scores^T = mfma32(Kfrag, Qfrag); O^T = mfma32(Vtfrag, Pfrag). 1-deep K/V prefetch.
__global__ __launch_bounds__(256) void attn_kernel(
    const short* __restrict__ Qb, const short* __restrict__ Kb,
    const short* __restrict__ Vt, short* __restrict__ ctx) {
  __shared__ short sO[4][32 * 72];
  const int bid = blockIdx.x;        // 0..511
  const int xcd = bid & 7;
  const int y = bid >> 3;            // 0..63
  const int p = y >> 1;              // pair 0..31
  const int bhg = xcd * 2 + (y & 1); // 0..15
  const int tid = threadIdx.x;
  const int w = tid >> 6, l = tid & 63;
  const int bh = bhg * 4 + w;
  const int b = bh >> 4, h = bh & 15;
  const int q31 = l & 31, hi5 = l >> 5;
  const short* Qp = Qb + (size_t)bh * S_ * HD_;
  const short* Kp = Kb + (size_t)bh * S_ * HD_;
  const short* Vp = Vt + (size_t)bh * HD_ * S_;
  short* so = &sO[w][0];

  f32x16 ot0, ot1;
  float mrow, lsum;

  s16x8 qf[4];

  auto loadkv = [&](s16x8 (&kf)[4], s16x8 (&vf)[4], int t) {
    const int kv0 = t * 32;
#pragma unroll
    for (int c = 0; c < 4; ++c)
      kf[c] = *(const s16x8*)(Kp + (kv0 + q31) * HD_ + c * 16 + hi5 * 8);
    vf[0] = *(const s16x8*)(Vp + q31 * S_ + kv0 + hi5 * 8);
    vf[1] = *(const s16x8*)(Vp + q31 * S_ + kv0 + 16 + hi5 * 8);
    vf[2] = *(const s16x8*)(Vp + (32 + q31) * S_ + kv0 + hi5 * 8);
    vf[3] = *(const s16x8*)(Vp + (32 + q31) * S_ + kv0 + 16 + hi5 * 8);
  };

  auto compute = [&](const s16x8 (&kf)[4], const s16x8 (&vf)[4], bool diag) {
    f32x16 s;
#pragma unroll
    for (int r = 0; r < 16; ++r) s[r] = 0.f;
    s = mfma32(kf[0], qf[0], s);
    s = mfma32(kf[1], qf[1], s);
    s = mfma32(kf[2], qf[2], s);
    s = mfma32(kf[3], qf[3], s);
    if (diag) {
#pragma unroll
      for (int r = 0; r < 16; ++r) {
        int kvpat = (r & 3) + 8 * (r >> 2) + 4 * hi5;
        if (kvpat > q31) s[r] = -1e30f;
      }
    }
    float m = s[0];
#pragma unroll
    for (int r = 1; r < 16; ++r) m = fmaxf(m, s[r]);
    m = fmaxf(m, __shfl_xor(m, 32));
    if (!__all(m <= mrow + 8.f)) {           // defer-max: rescale only on real growth
      float mn = fmaxf(mrow, m);
      float alpha = exp2f(mrow - mn);
      lsum *= alpha;
#pragma unroll
      for (int r = 0; r < 16; ++r) { ot0[r] *= alpha; ot1[r] *= alpha; }
      mrow = mn;
    }
    float p16[16];
    float rs = 0.f;
#pragma unroll
    for (int r = 0; r < 16; ++r) { p16[r] = exp2f(s[r] - mrow); rs += p16[r]; }
    rs += __shfl_xor(rs, 32);
    lsum += rs;
    unsigned pk01 = pkbf(p16[0], p16[1]),  pk23 = pkbf(p16[2], p16[3]);
    unsigned pk45 = pkbf(p16[4], p16[5]),  pk67 = pkbf(p16[6], p16[7]);
    unsigned pk89 = pkbf(p16[8], p16[9]),  pkAB = pkbf(p16[10], p16[11]);
    unsigned pkCD = pkbf(p16[12], p16[13]), pkEF = pkbf(p16[14], p16[15]);
    unsigned sx01 = (unsigned)__shfl_xor((int)pk01, 32);
    unsigned sx23 = (unsigned)__shfl_xor((int)pk23, 32);
    unsigned sx45 = (unsigned)__shfl_xor((int)pk45, 32);
    unsigned sx67 = (unsigned)__shfl_xor((int)pk67, 32);
    unsigned sx89 = (unsigned)__shfl_xor((int)pk89, 32);
    unsigned sxAB = (unsigned)__shfl_xor((int)pkAB, 32);
    unsigned sxCD = (unsigned)__shfl_xor((int)pkCD, 32);
    unsigned sxEF = (unsigned)__shfl_xor((int)pkEF, 32);
    union { u32x4 u; s16x8 v; } c0, c1;
    c0.u = hi5 ? (u32x4){sx45, sx67, pk45, pk67} : (u32x4){pk01, pk23, sx01, sx23};
    c1.u = hi5 ? (u32x4){sxCD, sxEF, pkCD, pkEF} : (u32x4){pk89, pkAB, sx89, sxAB};
    s16x8 pf0 = c0.v, pf1 = c1.v;
    ot0 = mfma32(vf[0], pf0, ot0);
    ot0 = mfma32(vf[1], pf1, ot0);
    ot1 = mfma32(vf[2], pf0, ot1);
    ot1 = mfma32(vf[3], pf1, ot1);
  };

  for (int half = 0; half < 2; ++half) {
    const int strip = half ? (63 - p) : p;
    const int nt = strip + 1;
    const int qw = strip * 32;
#pragma unroll
    for (int c = 0; c < 4; ++c)
      qf[c] = *(const s16x8*)(Qp + (qw + q31) * HD_ + c * 16 + hi5 * 8);
#pragma unroll
    for (int r = 0; r < 16; ++r) { ot0[r] = 0.f; ot1[r] = 0.f; }
    mrow = -1e30f; lsum = 0.f;

    s16x8 ka[4], va[4], kb2[4], vb2[4];
    loadkv(ka, va, 0);
    int t = 0;
    while (true) {
      if (t + 1 < nt) loadkv(kb2, vb2, t + 1);
      compute(ka, va, t == nt - 1);
      ++t; if (t >= nt) break;
      if (t + 1 < nt) loadkv(ka, va, t + 1);
      compute(kb2, vb2, t == nt - 1);
      ++t; if (t >= nt) break;
    }

    // epilogue: O^T regs -> per-wave LDS -> coalesced ctx rows
    float rl = 1.0f / lsum;
#pragma unroll
    for (int t2 = 0; t2 < 2; ++t2)
#pragma unroll
      for (int g = 0; g < 4; ++g) {
        float v0 = (t2 ? ot1[4 * g + 0] : ot0[4 * g + 0]) * rl;
        float v1 = (t2 ? ot1[4 * g + 1] : ot0[4 * g + 1]) * rl;
        float v2 = (t2 ? ot1[4 * g + 2] : ot0[4 * g + 2]) * rl;
        float v3 = (t2 ? ot1[4 * g + 3] : ot0[4 * g + 3]) * rl;
        int hdb = 32 * t2 + 8 * g + 4 * hi5;
        *(uint2*)(so + q31 * 72 + hdb) = make_uint2(pkbf(v0, v1), pkbf(v2, v3));
      }
    __syncthreads();
#pragma unroll
    for (int i = 0; i < 4; ++i) {
      int rr = l >> 1;
      int cb = (l & 1) * 8 + i * 16;
      s16x8 ov = *(const s16x8*)(so + rr * 72 + cb);
      *(s16x8*)(ctx + ((size_t)(b * S_ + qw + rr)) * D_ + h * 64 + cb) = ov;
    }
    __syncthreads();  // sO safe to reuse in next half
  }
}

extern "C" void kernel_launch(void* const* d_in, const int* in_sizes, int n_in,
                              void* d_out, int out_size, void* d_ws, size_t ws_size,
                              hipStream_t stream) {
  const float* x  = (const float*)d_in[0];
  const float* Wq = (const float*)d_in[1];
  const float* Wk = (const float*)d_in[2];
  const float* Wv = (const float*)d_in[3];
  const float* Wo = (const float*)d_in[4];
  float* out = (float*)d_out;

  char* ws = (char*)d_ws;
  size_t off = 0;
  auto alloc = [&](size_t bytes) {
    void* p = ws + off;
    off += (bytes + 255) & ~(size_t)255;
    return p;
  };
  short* xb   = (short*)alloc((size_t)M_TOT * D_ * 2);
  short* WqT  = (short*)alloc((size_t)D_ * D_ * 2);
  short* WkT  = (short*)alloc((size_t)D_ * D_ * 2);
  short* WvT  = (short*)alloc((size_t)D_ * D_ * 2);
  short* WoT  = (short*)alloc((size_t)D_ * D_ * 2);
  short* Qb   = (short*)alloc((size_t)B_ * H_ * S_ * HD_ * 2);
  short* Kb   = (short*)alloc((size_t)B_ * H_ * S_ * HD_ * 2);
  short* Vt   = (short*)alloc((size_t)B_ * H_ * S_ * HD_ * 2);
  short* ctxb = (short*)alloc((size_t)M_TOT * D_ * 2);

  cast_x_kernel<<<(M_TOT * D_) / (256 * 8), 256, 0, stream>>>(x, xb);
  transpose_cast_kernel<<<dim3(D_ / 32, D_ / 32, 4), dim3(32, 8, 1), 0, stream>>>(
      Wq, Wk, Wv, Wo, WqT, WkT, WvT, WoT);
  gemm_qkv_kernel<<<dim3(M_TOT / 128, D_ / 128, 3), 256, 0, stream>>>(
      xb, WqT, WkT, WvT, Qb, Kb, Vt);
  attn_kernel<<<dim3(512), 256, 0, stream>>>(Qb, Kb, Vt, ctxb);
  gemm_out_kernel<<<dim3(M_TOT / 128, D_ / 128), 256, 0, stream>>>(ctxb, WoT, out);
}